// Round 6
// baseline (418.610 us; speedup 1.0000x reference)
//
#include <hip/hip_runtime.h>
#include <math.h>

#define NMODES 32
#define NPAIR 496
#define TAYLOR_N 12

// T2 matrix in module-scope device memory (d_ws may be zero-sized).
__device__ float2 g_T2[NMODES * NMODES];

__device__ __forceinline__ float2 cmul(float2 a, float2 b) {
    return make_float2(a.x * b.x - a.y * b.y, a.x * b.y + a.y * b.x);
}

// ---------------------------------------------------------------------------
// Setup kernel: one block of 1024 threads builds T2 (32x32 complex).
// (unchanged from the round-0/3/5 PASSING kernels)
// ---------------------------------------------------------------------------
__global__ __launch_bounds__(1024) void setup_kernel(const float* __restrict__ params,
                                                     const float* __restrict__ kappa) {
    __shared__ float2 X[NMODES][NMODES];
    __shared__ float2 R[NMODES][NMODES];
    __shared__ float2 W[NMODES][NMODES];
    __shared__ float2 Aug[NMODES][2 * NMODES];
    __shared__ int sh_s;
    __shared__ float sh_scale;
    __shared__ int sh_piv;
    __shared__ float2 sh_pivrec;

    const int tid = threadIdx.x;
    const int i = tid >> 5;
    const int j = tid & 31;

    // --- build H ---
    float2 h;
    if (i == j) {
        float d;
        if (i < 31) {
            d = params[2 * NPAIR + i];
        } else {
            d = 0.0f;
            for (int r = 0; r < 31; ++r) d -= params[2 * NPAIR + r];
        }
        h = make_float2(d, 0.0f);
    } else {
        int a = (i < j) ? i : j;
        int b = (i < j) ? j : i;
        int idx = 31 * a - (a * (a - 1)) / 2 + (b - a - 1);  // row-major triu
        float re = params[idx];
        float im = params[NPAIR + idx];
        h = (i < j) ? make_float2(re, im) : make_float2(re, -im);
    }
    X[i][j] = h;
    __syncthreads();

    // --- inf-norm (wave 0, parallel rows + shuffle max-reduce) ---
    if (tid < 32) {
        float s = 0.0f;
        for (int c = 0; c < NMODES; ++c) {
            float2 v = X[tid][c];
            s += sqrtf(v.x * v.x + v.y * v.y);
        }
        for (int off = 16; off > 0; off >>= 1)
            s = fmaxf(s, __shfl_down(s, off));
        if (tid == 0) {
            int sc_n = 0;
            float sc = 1.0f;
            while (s > 0.25f && sc_n < 40) { s *= 0.5f; sc *= 0.5f; ++sc_n; }
            sh_s = sc_n;
            sh_scale = sc;
        }
    }
    __syncthreads();

    // --- X = (i*H) * 2^{-s} ---
    {
        float sc = sh_scale;
        float2 v = X[i][j];
        X[i][j] = make_float2(-v.y * sc, v.x * sc);
    }
    __syncthreads();

    // --- Taylor via Horner: R = I; for k=N..1: R = I + (X*R)/k ---
    R[i][j] = make_float2((i == j) ? 1.0f : 0.0f, 0.0f);
    __syncthreads();
    for (int k = TAYLOR_N; k >= 1; --k) {
        float2 acc = make_float2(0.0f, 0.0f);
        for (int kk = 0; kk < NMODES; ++kk) {
            float2 a = X[i][kk];
            float2 b = R[kk][j];
            acc.x = fmaf(a.x, b.x, fmaf(-a.y, b.y, acc.x));
            acc.y = fmaf(a.x, b.y, fmaf(a.y, b.x, acc.y));
        }
        __syncthreads();
        float invk = 1.0f / (float)k;
        R[i][j] = make_float2(((i == j) ? 1.0f : 0.0f) + acc.x * invk, acc.y * invk);
        __syncthreads();
    }

    // --- squarings ---
    {
        int s = sh_s;
        for (int q = 0; q < s; ++q) {
            float2 acc = make_float2(0.0f, 0.0f);
            for (int kk = 0; kk < NMODES; ++kk) {
                float2 a = R[i][kk];
                float2 b = R[kk][j];
                acc.x = fmaf(a.x, b.x, fmaf(-a.y, b.y, acc.x));
                acc.y = fmaf(a.x, b.y, fmaf(a.y, b.x, acc.y));
            }
            __syncthreads();
            R[i][j] = acc;
            __syncthreads();
        }
    }

    // --- W = U^T U (no conjugation) ---
    {
        float2 acc = make_float2(0.0f, 0.0f);
        for (int kk = 0; kk < NMODES; ++kk) {
            float2 a = R[kk][i];
            float2 b = R[kk][j];
            acc.x = fmaf(a.x, b.x, fmaf(-a.y, b.y, acc.x));
            acc.y = fmaf(a.x, b.y, fmaf(a.y, b.x, acc.y));
        }
        W[i][j] = acc;
    }
    __syncthreads();

    // --- augmented [1.1 I - W | W] ---
    {
        float2 w = W[i][j];
        Aug[i][j] = make_float2(((i == j) ? 1.1f : 0.0f) - w.x, -w.y);
        Aug[i][j + NMODES] = w;
    }
    __syncthreads();

    // --- Gauss-Jordan with partial pivoting; right half -> mix ---
    for (int p = 0; p < NMODES; ++p) {
        if (tid < 32) {  // parallel argmax pivot search (wave 0)
            float2 v = Aug[tid][p];
            float mag = (tid >= p) ? (v.x * v.x + v.y * v.y) : -1.0f;
            int idx = tid;
            for (int off = 16; off > 0; off >>= 1) {
                float omg = __shfl_down(mag, off);
                int oi = __shfl_down(idx, off);
                if (omg > mag) { mag = omg; idx = oi; }
            }
            if (tid == 0) sh_piv = idx;
        }
        __syncthreads();
        int piv = sh_piv;
        if (piv != p && i == p) {
            float2 a0 = Aug[p][j], b0 = Aug[piv][j];
            float2 a1 = Aug[p][j + NMODES], b1 = Aug[piv][j + NMODES];
            Aug[p][j] = b0; Aug[piv][j] = a0;
            Aug[p][j + NMODES] = b1; Aug[piv][j + NMODES] = a1;
        }
        __syncthreads();
        if (tid == 0) {
            float2 d = Aug[p][p];
            float den = d.x * d.x + d.y * d.y;
            sh_pivrec = make_float2(d.x / den, -d.y / den);
        }
        __syncthreads();
        if (i == p) {
            float2 pr = sh_pivrec;
            Aug[p][j] = cmul(Aug[p][j], pr);
            Aug[p][j + NMODES] = cmul(Aug[p][j + NMODES], pr);
        }
        __syncthreads();
        float2 f = Aug[i][p];
        __syncthreads();
        if (i != p) {
            float2 rp0 = Aug[p][j];
            float2 rp1 = Aug[p][j + NMODES];
            float2 v0 = Aug[i][j];
            float2 v1 = Aug[i][j + NMODES];
            v0.x -= f.x * rp0.x - f.y * rp0.y;
            v0.y -= f.x * rp0.y + f.y * rp0.x;
            v1.x -= f.x * rp1.x - f.y * rp1.y;
            v1.y -= f.x * rp1.y + f.y * rp1.x;
            Aug[i][j] = v0;
            Aug[i][j + NMODES] = v1;
        }
        __syncthreads();
    }

    // --- T2 ---
    {
        float2 mix = Aug[i][j + NMODES];
        float kk2 = fabsf(kappa[i]) * fabsf(kappa[j]);
        float re = -kk2 * (((i == j) ? 0.5f : 0.0f) + mix.x);
        float im = -kk2 * mix.y;
        g_T2[i * NMODES + j] = make_float2(re, im);
    }
}

// ---------------------------------------------------------------------------
// Main ODE kernel — XOR broadcast-tree v5, ALL-VALU cross-lane (no DS in the
// RK chain).
//
// Round-5 accounting: wall 905 cyc/eval-round == 4 x ~226-cyc serial eval
// critical path (latency-bound, 2 waves/SIMD can't cover). Largest item:
// the 4 ds_bpermute combine (~80-100 cyc LDS round-trip) per eval.
//
// New layout (blocks of T2 = [A B; C D], u = y[0:16], v = y[16:32]):
//   r0 (lanes  0-15): seeds u, block A (rows lo, cols lo) -> P[p]    (out-lo)
//   r1 (lanes 16-31): seeds u, block C (rows hi, cols lo) -> P[16+p] (out-hi)
//   r2 (lanes 32-47): seeds v, block B (rows lo, cols hi) -> P[32+p] (out-lo)
//   r3 (lanes 48-63): seeds v, block D (rows hi, cols hi) -> P[48+p] (out-hi)
// Combine (both partials at lane distance 32): v_permlane32_swap_b32 + add
// gives every lane k[lane&31]; each lane OWNS mode lane&31 (RK state, omega,
// nonlinear term). Seed redistribution for the next stage (r1 needs r0's y,
// r2 needs r3's y): one v_permlane16_swap_b32 + select on (lane>=32).
// Builtins are HW-proven (guide T12); round-2's failure was hand-rolled
// tied-operand asm, which the builtin's two-result modeling avoids.
// __has_builtin fallbacks: ds_bpermute combine (round-3-proven) and
// ds_swizzle xor16 (ISA BitMode 0x401F).
// Tree + cfma structure identical to the round-5 PASSING kernel.
// ---------------------------------------------------------------------------
template<int CTRL>
__device__ __forceinline__ float2 dppshuf(float2 v) {
    return make_float2(
        __int_as_float(__builtin_amdgcn_mov_dpp(__float_as_int(v.x), CTRL, 0xF, 0xF, true)),
        __int_as_float(__builtin_amdgcn_mov_dpp(__float_as_int(v.y), CTRL, 0xF, 0xF, true)));
}

#define QP_X1 0xB1   // quad_perm [1,0,3,2]   == xor 1
#define QP_X2 0x4E   // quad_perm [2,3,0,1]   == xor 2
#define QP_X3 0x1B   // quad_perm [3,2,1,0]   == xor 3
#define HM_X7 0x141  // row_half_mirror       == xor 7  (within 8)
#define RM_XF 0x140  // row_mirror            == xor 15 (within 16)

typedef unsigned int v2u __attribute__((ext_vector_type(2)));

__device__ __forceinline__ void cfma(float2& acc, float2 c, float2 w) {
    acc.x = fmaf(c.x, w.x, fmaf(-c.y, w.y, acc.x));
    acc.y = fmaf(c.x, w.y, fmaf(c.y, w.x, acc.y));
}

__device__ __forceinline__ float bperm(int idx, float v) {
    return __int_as_float(__builtin_amdgcn_ds_bpermute(idx, __float_as_int(v)));
}

// sum of partials across lane <-> lane^32: every lane gets P[l&31] + P[(l&31)+32]
__device__ __forceinline__ float comb32(float x, int bp0) {
#if __has_builtin(__builtin_amdgcn_permlane32_swap)
    v2u r = __builtin_amdgcn_permlane32_swap(__float_as_uint(x), __float_as_uint(x),
                                             false, false);
    return __uint_as_float(r.x) + __uint_as_float(r.y);
#else
    return bperm(bp0, x) + bperm(bp0 + 128, x);  // round-3-proven fallback
#endif
}

template<int MASK>
__device__ __forceinline__ float2 swzshuf(float2 v) {
    return make_float2(
        __int_as_float(__builtin_amdgcn_ds_swizzle(__float_as_int(v.x), MASK)),
        __int_as_float(__builtin_amdgcn_ds_swizzle(__float_as_int(v.y), MASK)));
}

// ring seed for the next stage from the per-lane owned state y:
//   r0 -> own y (u), r1 -> y from r0 (u), r2 -> y from r3 (v), r3 -> own y (v)
__device__ __forceinline__ float2 seed_of(float2 y, bool upper) {
#if __has_builtin(__builtin_amdgcn_permlane16_swap)
    // equal inputs: r.x = {y_r0,y_r0,y_r2,y_r2}, r.y = {y_r1,y_r1,y_r3,y_r3}
    v2u rx = __builtin_amdgcn_permlane16_swap(__float_as_uint(y.x), __float_as_uint(y.x),
                                              false, false);
    v2u ry = __builtin_amdgcn_permlane16_swap(__float_as_uint(y.y), __float_as_uint(y.y),
                                              false, false);
    // lower lanes (r0,r1) want the r0/r... r0: own=rx.x, r1: y_r0=rx.x;
    // upper lanes (r2,r3): r2 wants y_r3=rx.y's...  r2: y_r3 = .y, r3: own = .y
    return make_float2(upper ? __uint_as_float(rx.y) : __uint_as_float(rx.x),
                       upper ? __uint_as_float(ry.y) : __uint_as_float(ry.x));
#else
    // fallback: lane^16 swizzle; r1 gets y_r0, r2 gets y_r3 (what they need);
    // r0,r3 keep their own.
    float2 sw = swzshuf<0x401F>(y);
    int rrow = (int)(threadIdx.x >> 4);
    bool mid = (rrow == 1) || (rrow == 2);
    return make_float2(mid ? sw.x : y.x, mid ? sw.y : y.y);
#endif
}

__device__ __forceinline__ float2 feval(const float2* __restrict__ t2,
                                        float2 seed, float2 zloc,
                                        float om, float nl2, int bp0) {
    // --- broadcast tree: w[s].lane(p) = seed.lane(p^s), depth <= 3 ---
    float2 w1 = dppshuf<QP_X1>(seed);
    float2 w2 = dppshuf<QP_X2>(seed);
    float2 w3 = dppshuf<QP_X3>(seed);
    float2 w7 = dppshuf<HM_X7>(seed);
    float2 wF = dppshuf<RM_XF>(seed);
    float2 w4 = dppshuf<QP_X3>(w7);   // 7^3 = 4
    float2 w5 = dppshuf<QP_X2>(w7);   // 7^2 = 5
    float2 w6 = dppshuf<QP_X1>(w7);   // 7^1 = 6
    float2 w8 = dppshuf<HM_X7>(wF);   // 15^7 = 8
    float2 wC = dppshuf<QP_X3>(wF);   // 15^3 = 12
    float2 wD = dppshuf<QP_X2>(wF);   // 15^2 = 13
    float2 wE = dppshuf<QP_X1>(wF);   // 15^1 = 14
    float2 w9 = dppshuf<QP_X1>(w8);   // 8^1 = 9
    float2 wA = dppshuf<QP_X2>(w8);   // 8^2 = 10
    float2 wB = dppshuf<QP_X3>(w8);   // 8^3 = 11

    // --- 16 cfmas over 4 independent accumulators ---
    float2 a0 = make_float2(0.0f, 0.0f), a1 = make_float2(0.0f, 0.0f);
    float2 a2 = make_float2(0.0f, 0.0f), a3 = make_float2(0.0f, 0.0f);
    cfma(a0, t2[0],  seed);
    cfma(a1, t2[1],  w1);
    cfma(a2, t2[2],  w2);
    cfma(a3, t2[3],  w3);
    cfma(a0, t2[4],  w4);
    cfma(a1, t2[5],  w5);
    cfma(a2, t2[6],  w6);
    cfma(a3, t2[7],  w7);
    cfma(a0, t2[8],  w8);
    cfma(a1, t2[9],  w9);
    cfma(a2, t2[10], wA);
    cfma(a3, t2[11], wB);
    cfma(a0, t2[12], wC);
    cfma(a1, t2[13], wD);
    cfma(a2, t2[14], wE);
    cfma(a3, t2[15], wF);

    float px = (a0.x + a1.x) + (a2.x + a3.x);
    float py = (a0.y + a1.y) + (a2.y + a3.y);
    // combine the two block-partials of every output row (lane distance 32)
    float kx = comb32(px, bp0);
    float ky = comb32(py, bp0);

    // local nonlinear/frequency term for the OWNED mode
    float wf = fmaf(nl2, fmaf(zloc.x, zloc.x, zloc.y * zloc.y), om);
    return make_float2(kx - wf * zloc.y, ky + wf * zloc.x);
}

__global__ __launch_bounds__(64) void ode_kernel(const float* __restrict__ A0r,
                                                 const float* __restrict__ A0i,
                                                 const float* __restrict__ omega,
                                                 const float* __restrict__ nln,
                                                 float* __restrict__ out,
                                                 long long out_size) {
    const int lane = threadIdx.x;
    const int p = lane & 15;
    const int mstar = lane & 31;               // mode this lane owns
    const bool upper = lane >= 32;             // rows r2,r3 (seed the v-half)
    const int hs = upper ? 1 : 0;              // block column half
    const int bp0 = 4 * mstar;                 // bpermute fallback index
    const int b = blockIdx.x;

    // T2 block diagonal for this lane, indexed by xor mask s:
    // t2[s] = T2[mstar][16*hs + (p^s)]  (row = owned mode = 16*((lane>>4)&1)+p)
    float2 t2[16];
#pragma unroll
    for (int s = 0; s < 16; ++s)
        t2[s] = g_T2[mstar * 32 + 16 * hs + (p ^ s)];

    const float om = omega[mstar];
    const float nl = nln[0];
    const float nl2 = nl * nl;
    const float dt = 1.0f / 199.0f;
    const float hdt = 0.5f * dt;
    const float sdt = dt / 6.0f;

    // initial state for the owned mode (one LDS bounce; lane l<32 owns mode l)
    __shared__ float2 ainit[32];
    if (lane < 32) {
        float2 v;
        if (lane < 24) v = make_float2(A0r[b * 24 + lane], A0i[b * 24 + lane]);
        else           v = make_float2(1.0f, 0.0f);
        ainit[lane] = v;
    }
    __syncthreads();
    float2 a = ainit[mstar];

    // t = 0 output (real plane only, guarded); lane l < 32 holds mode l
    long long o = (long long)b * 32 + lane;
    if (lane < 32 && o < out_size) out[o] = a.x;

    float2 s0 = seed_of(a, upper);

    for (int t = 1; t < 200; ++t) {
        float2 k1 = feval(t2, s0, a, om, nl2, bp0);
        float2 y = make_float2(fmaf(hdt, k1.x, a.x), fmaf(hdt, k1.y, a.y));
        float2 sd = seed_of(y, upper);
        float2 k2 = feval(t2, sd, y, om, nl2, bp0);
        y = make_float2(fmaf(hdt, k2.x, a.x), fmaf(hdt, k2.y, a.y));
        sd = seed_of(y, upper);
        float2 k3 = feval(t2, sd, y, om, nl2, bp0);
        y = make_float2(fmaf(dt, k3.x, a.x), fmaf(dt, k3.y, a.y));
        sd = seed_of(y, upper);
        float2 k4 = feval(t2, sd, y, om, nl2, bp0);

        a.x = fmaf(sdt, fmaf(2.0f, k2.x + k3.x, k1.x + k4.x), a.x);
        a.y = fmaf(sdt, fmaf(2.0f, k2.y + k3.y, k1.y + k4.y), a.y);
        s0 = seed_of(a, upper);

        o += 65536;  // 2048 * 32
        if (lane < 32 && o < out_size) out[o] = a.x;
    }
}

extern "C" void kernel_launch(void* const* d_in, const int* in_sizes, int n_in,
                              void* d_out, int out_size, void* d_ws, size_t ws_size,
                              hipStream_t stream) {
    const float* A0r = (const float*)d_in[0];
    const float* A0i = (const float*)d_in[1];
    const float* omega = (const float*)d_in[2];
    const float* kappa = (const float*)d_in[3];
    const float* nln = (const float*)d_in[4];
    const float* params = (const float*)d_in[5];

    setup_kernel<<<1, 1024, 0, stream>>>(params, kappa);
    ode_kernel<<<2048, 64, 0, stream>>>(A0r, A0i, omega, nln,
                                        (float*)d_out, (long long)out_size);
}

// Round 7
// 393.782 us; speedup vs baseline: 1.0631x; 1.0631x over previous
//
#include <hip/hip_runtime.h>
#include <math.h>

#define NMODES 32
#define NPAIR 496
#define TAYLOR_N 12

// T2 matrix in module-scope device memory (d_ws may be zero-sized).
__device__ float2 g_T2[NMODES * NMODES];

__device__ __forceinline__ float2 cmul(float2 a, float2 b) {
    return make_float2(a.x * b.x - a.y * b.y, a.x * b.y + a.y * b.x);
}

// ---------------------------------------------------------------------------
// Setup kernel: one block of 1024 threads builds T2 (32x32 complex).
// (unchanged from the round-0/3/5 PASSING kernels)
// ---------------------------------------------------------------------------
__global__ __launch_bounds__(1024) void setup_kernel(const float* __restrict__ params,
                                                     const float* __restrict__ kappa) {
    __shared__ float2 X[NMODES][NMODES];
    __shared__ float2 R[NMODES][NMODES];
    __shared__ float2 W[NMODES][NMODES];
    __shared__ float2 Aug[NMODES][2 * NMODES];
    __shared__ int sh_s;
    __shared__ float sh_scale;
    __shared__ int sh_piv;
    __shared__ float2 sh_pivrec;

    const int tid = threadIdx.x;
    const int i = tid >> 5;
    const int j = tid & 31;

    // --- build H ---
    float2 h;
    if (i == j) {
        float d;
        if (i < 31) {
            d = params[2 * NPAIR + i];
        } else {
            d = 0.0f;
            for (int r = 0; r < 31; ++r) d -= params[2 * NPAIR + r];
        }
        h = make_float2(d, 0.0f);
    } else {
        int a = (i < j) ? i : j;
        int b = (i < j) ? j : i;
        int idx = 31 * a - (a * (a - 1)) / 2 + (b - a - 1);  // row-major triu
        float re = params[idx];
        float im = params[NPAIR + idx];
        h = (i < j) ? make_float2(re, im) : make_float2(re, -im);
    }
    X[i][j] = h;
    __syncthreads();

    // --- inf-norm (wave 0, parallel rows + shuffle max-reduce) ---
    if (tid < 32) {
        float s = 0.0f;
        for (int c = 0; c < NMODES; ++c) {
            float2 v = X[tid][c];
            s += sqrtf(v.x * v.x + v.y * v.y);
        }
        for (int off = 16; off > 0; off >>= 1)
            s = fmaxf(s, __shfl_down(s, off));
        if (tid == 0) {
            int sc_n = 0;
            float sc = 1.0f;
            while (s > 0.25f && sc_n < 40) { s *= 0.5f; sc *= 0.5f; ++sc_n; }
            sh_s = sc_n;
            sh_scale = sc;
        }
    }
    __syncthreads();

    // --- X = (i*H) * 2^{-s} ---
    {
        float sc = sh_scale;
        float2 v = X[i][j];
        X[i][j] = make_float2(-v.y * sc, v.x * sc);
    }
    __syncthreads();

    // --- Taylor via Horner: R = I; for k=N..1: R = I + (X*R)/k ---
    R[i][j] = make_float2((i == j) ? 1.0f : 0.0f, 0.0f);
    __syncthreads();
    for (int k = TAYLOR_N; k >= 1; --k) {
        float2 acc = make_float2(0.0f, 0.0f);
        for (int kk = 0; kk < NMODES; ++kk) {
            float2 a = X[i][kk];
            float2 b = R[kk][j];
            acc.x = fmaf(a.x, b.x, fmaf(-a.y, b.y, acc.x));
            acc.y = fmaf(a.x, b.y, fmaf(a.y, b.x, acc.y));
        }
        __syncthreads();
        float invk = 1.0f / (float)k;
        R[i][j] = make_float2(((i == j) ? 1.0f : 0.0f) + acc.x * invk, acc.y * invk);
        __syncthreads();
    }

    // --- squarings ---
    {
        int s = sh_s;
        for (int q = 0; q < s; ++q) {
            float2 acc = make_float2(0.0f, 0.0f);
            for (int kk = 0; kk < NMODES; ++kk) {
                float2 a = R[i][kk];
                float2 b = R[kk][j];
                acc.x = fmaf(a.x, b.x, fmaf(-a.y, b.y, acc.x));
                acc.y = fmaf(a.x, b.y, fmaf(a.y, b.x, acc.y));
            }
            __syncthreads();
            R[i][j] = acc;
            __syncthreads();
        }
    }

    // --- W = U^T U (no conjugation) ---
    {
        float2 acc = make_float2(0.0f, 0.0f);
        for (int kk = 0; kk < NMODES; ++kk) {
            float2 a = R[kk][i];
            float2 b = R[kk][j];
            acc.x = fmaf(a.x, b.x, fmaf(-a.y, b.y, acc.x));
            acc.y = fmaf(a.x, b.y, fmaf(a.y, b.x, acc.y));
        }
        W[i][j] = acc;
    }
    __syncthreads();

    // --- augmented [1.1 I - W | W] ---
    {
        float2 w = W[i][j];
        Aug[i][j] = make_float2(((i == j) ? 1.1f : 0.0f) - w.x, -w.y);
        Aug[i][j + NMODES] = w;
    }
    __syncthreads();

    // --- Gauss-Jordan with partial pivoting; right half -> mix ---
    for (int p = 0; p < NMODES; ++p) {
        if (tid < 32) {  // parallel argmax pivot search (wave 0)
            float2 v = Aug[tid][p];
            float mag = (tid >= p) ? (v.x * v.x + v.y * v.y) : -1.0f;
            int idx = tid;
            for (int off = 16; off > 0; off >>= 1) {
                float omg = __shfl_down(mag, off);
                int oi = __shfl_down(idx, off);
                if (omg > mag) { mag = omg; idx = oi; }
            }
            if (tid == 0) sh_piv = idx;
        }
        __syncthreads();
        int piv = sh_piv;
        if (piv != p && i == p) {
            float2 a0 = Aug[p][j], b0 = Aug[piv][j];
            float2 a1 = Aug[p][j + NMODES], b1 = Aug[piv][j + NMODES];
            Aug[p][j] = b0; Aug[piv][j] = a0;
            Aug[p][j + NMODES] = b1; Aug[piv][j + NMODES] = a1;
        }
        __syncthreads();
        if (tid == 0) {
            float2 d = Aug[p][p];
            float den = d.x * d.x + d.y * d.y;
            sh_pivrec = make_float2(d.x / den, -d.y / den);
        }
        __syncthreads();
        if (i == p) {
            float2 pr = sh_pivrec;
            Aug[p][j] = cmul(Aug[p][j], pr);
            Aug[p][j + NMODES] = cmul(Aug[p][j + NMODES], pr);
        }
        __syncthreads();
        float2 f = Aug[i][p];
        __syncthreads();
        if (i != p) {
            float2 rp0 = Aug[p][j];
            float2 rp1 = Aug[p][j + NMODES];
            float2 v0 = Aug[i][j];
            float2 v1 = Aug[i][j + NMODES];
            v0.x -= f.x * rp0.x - f.y * rp0.y;
            v0.y -= f.x * rp0.y + f.y * rp0.x;
            v1.x -= f.x * rp1.x - f.y * rp1.y;
            v1.y -= f.x * rp1.y + f.y * rp1.x;
            Aug[i][j] = v0;
            Aug[i][j + NMODES] = v1;
        }
        __syncthreads();
    }

    // --- T2 ---
    {
        float2 mix = Aug[i][j + NMODES];
        float kk2 = fabsf(kappa[i]) * fabsf(kappa[j]);
        float re = -kk2 * (((i == j) ? 0.5f : 0.0f) + mix.x);
        float im = -kk2 * mix.y;
        g_T2[i * NMODES + j] = make_float2(re, im);
    }
}

// ===========================================================================
// Main ODE kernel — PIPE-MIX: half the blocks run the round-0 LDS-staged
// path (DS-pipe-heavy: ~102 DS-cyc/eval, VALU ~194), half run the round-5
// DPP broadcast-tree path (VALU-heavy: ~339 VALU-cyc/eval, DS ~25).
//
// Cross-round ledger (SIMD-cyc/batch-eval): R0=406 (DS pipe 100%, VALU 48%),
// R5=452 (VALU 76%, DS ~5%). Homogeneous launches saturate ONE pipe and idle
// the other. With 4+4 waves/CU of each type, per-eval window: DS ~508 cyc/CU
// (was 816), VALU ~533 cyc/SIMD (was 688 busy / 905 wall) -> predicted wall
// ~560-650 cyc/eval. Both paths are byte-for-byte the PASSING round-0 /
// round-5 code; the only new code is the block-parity branch (block-uniform,
// so the LDS path's __syncthreads stays legal).
// ===========================================================================

// ------------------------------ DPP path (round 5) -------------------------
template<int CTRL>
__device__ __forceinline__ float2 dppshuf(float2 v) {
    return make_float2(
        __int_as_float(__builtin_amdgcn_mov_dpp(__float_as_int(v.x), CTRL, 0xF, 0xF, true)),
        __int_as_float(__builtin_amdgcn_mov_dpp(__float_as_int(v.y), CTRL, 0xF, 0xF, true)));
}

#define QP_X1 0xB1   // quad_perm [1,0,3,2]   == xor 1
#define QP_X2 0x4E   // quad_perm [2,3,0,1]   == xor 2
#define QP_X3 0x1B   // quad_perm [3,2,1,0]   == xor 3
#define HM_X7 0x141  // row_half_mirror       == xor 7  (within 8)
#define RM_XF 0x140  // row_mirror            == xor 15 (within 16)

__device__ __forceinline__ void cfma(float2& acc, float2 c, float2 w) {
    acc.x = fmaf(c.x, w.x, fmaf(-c.y, w.y, acc.x));
    acc.y = fmaf(c.x, w.y, fmaf(c.y, w.x, acc.y));
}

__device__ __forceinline__ float bperm(int idx, float v) {
    return __int_as_float(__builtin_amdgcn_ds_bpermute(idx, __float_as_int(v)));
}

__device__ __forceinline__ float2 feval_dpp(const float2* __restrict__ t2,
                                            float2 z, float om, float nl2,
                                            int bp0, int bp1) {
    // broadcast tree: w[s].lane(p) = z.lane(p^s), depth <= 3
    float2 w1 = dppshuf<QP_X1>(z);
    float2 w2 = dppshuf<QP_X2>(z);
    float2 w3 = dppshuf<QP_X3>(z);
    float2 w7 = dppshuf<HM_X7>(z);
    float2 wF = dppshuf<RM_XF>(z);
    float2 w4 = dppshuf<QP_X3>(w7);   // 7^3 = 4
    float2 w5 = dppshuf<QP_X2>(w7);   // 7^2 = 5
    float2 w6 = dppshuf<QP_X1>(w7);   // 7^1 = 6
    float2 w8 = dppshuf<HM_X7>(wF);   // 15^7 = 8
    float2 wC = dppshuf<QP_X3>(wF);   // 15^3 = 12
    float2 wD = dppshuf<QP_X2>(wF);   // 15^2 = 13
    float2 wE = dppshuf<QP_X1>(wF);   // 15^1 = 14
    float2 w9 = dppshuf<QP_X1>(w8);   // 8^1 = 9
    float2 wA = dppshuf<QP_X2>(w8);   // 8^2 = 10
    float2 wB = dppshuf<QP_X3>(w8);   // 8^3 = 11

    float2 a0 = make_float2(0.0f, 0.0f), a1 = make_float2(0.0f, 0.0f);
    float2 a2 = make_float2(0.0f, 0.0f), a3 = make_float2(0.0f, 0.0f);
    cfma(a0, t2[0],  z);
    cfma(a1, t2[1],  w1);
    cfma(a2, t2[2],  w2);
    cfma(a3, t2[3],  w3);
    cfma(a0, t2[4],  w4);
    cfma(a1, t2[5],  w5);
    cfma(a2, t2[6],  w6);
    cfma(a3, t2[7],  w7);
    cfma(a0, t2[8],  w8);
    cfma(a1, t2[9],  w9);
    cfma(a2, t2[10], wA);
    cfma(a3, t2[11], wB);
    cfma(a0, t2[12], wC);
    cfma(a1, t2[13], wD);
    cfma(a2, t2[14], wE);
    cfma(a3, t2[15], wF);

    float px = (a0.x + a1.x) + (a2.x + a3.x);
    float py = (a0.y + a1.y) + (a2.y + a3.y);
    // partial(out-lo[p]) in lanes p and 32+p; partial(out-hi[p]) in lanes
    // 16+p and 48+p. bp0 = 4*mstar, bp1 = bp0 + 128. (round-3/5 proven)
    float kx = bperm(bp0, px) + bperm(bp1, px);
    float ky = bperm(bp0, py) + bperm(bp1, py);

    float wf = fmaf(nl2, fmaf(z.x, z.x, z.y * z.y), om);
    return make_float2(kx - wf * z.y, ky + wf * z.x);
}

__device__ void ode_dpp(int b, int lane,
                        const float* __restrict__ A0r,
                        const float* __restrict__ A0i,
                        const float* __restrict__ omega,
                        const float* __restrict__ nln,
                        float* __restrict__ out, long long out_size) {
    const int r = lane >> 4;
    const int p = lane & 15;
    const int ho = r & 1;                       // output half this row computes
    const int hr = (r == 1 || r == 2) ? 1 : 0;  // held (ring) half
    const int mstar = 16 * hr + p;              // mode this lane owns
    const int bp0 = 4 * mstar;
    const int bp1 = bp0 + 128;

    float2 t2[16];
    {
        const int row_g = 16 * ho + p;
#pragma unroll
        for (int s = 0; s < 16; ++s)
            t2[s] = g_T2[row_g * 32 + 16 * hr + (p ^ s)];
    }

    const float om = omega[mstar];
    const float nl = nln[0];
    const float nl2 = nl * nl;
    const float dt = 1.0f / 199.0f;
    const float hdt = 0.5f * dt;
    const float sdt = dt / 6.0f;

    __shared__ float2 ainit[32];
    if (lane < 32) {
        float2 v;
        if (lane < 24) v = make_float2(A0r[b * 24 + lane], A0i[b * 24 + lane]);
        else           v = make_float2(1.0f, 0.0f);
        ainit[lane] = v;
    }
    __syncthreads();
    float2 a = ainit[mstar];

    long long o = (long long)b * 32 + lane;
    if (lane < 32 && o < out_size) out[o] = a.x;

    for (int t = 1; t < 200; ++t) {
        float2 k1 = feval_dpp(t2, a, om, nl2, bp0, bp1);
        float2 z = make_float2(fmaf(hdt, k1.x, a.x), fmaf(hdt, k1.y, a.y));
        float2 k2 = feval_dpp(t2, z, om, nl2, bp0, bp1);
        z = make_float2(fmaf(hdt, k2.x, a.x), fmaf(hdt, k2.y, a.y));
        float2 k3 = feval_dpp(t2, z, om, nl2, bp0, bp1);
        z = make_float2(fmaf(dt, k3.x, a.x), fmaf(dt, k3.y, a.y));
        float2 k4 = feval_dpp(t2, z, om, nl2, bp0, bp1);

        a.x = fmaf(sdt, fmaf(2.0f, k2.x + k3.x, k1.x + k4.x), a.x);
        a.y = fmaf(sdt, fmaf(2.0f, k2.y + k3.y, k1.y + k4.y), a.y);

        o += 65536;  // 2048 * 32
        if (lane < 32 && o < out_size) out[o] = a.x;
    }
}

// ------------------------------ LDS path (round 0) -------------------------
// lane = (m = lane>>1, h = lane&1); half T2 row per lane; halves combine via
// __shfl_xor(.,1). Padded LDS: slot(k) = k + (k>=16 ? 2 : 0).
__device__ __forceinline__ float2 f_eval_lds(const float4* __restrict__ xq,
                                             float2 ym,
                                             const float2* __restrict__ t2h,
                                             float om, float nl2) {
    float2 acc0 = make_float2(0.0f, 0.0f);
    float2 acc1 = make_float2(0.0f, 0.0f);
#pragma unroll
    for (int j = 0; j < 8; ++j) {
        float4 v = xq[j];  // complex x[h*16+2j], x[h*16+2j+1]
        float2 ta = t2h[2 * j];
        float2 tb = t2h[2 * j + 1];
        acc0.x = fmaf(ta.x, v.x, acc0.x);
        acc0.x = fmaf(-ta.y, v.y, acc0.x);
        acc0.y = fmaf(ta.x, v.y, acc0.y);
        acc0.y = fmaf(ta.y, v.x, acc0.y);
        acc1.x = fmaf(tb.x, v.z, acc1.x);
        acc1.x = fmaf(-tb.y, v.w, acc1.x);
        acc1.y = fmaf(tb.x, v.w, acc1.y);
        acc1.y = fmaf(tb.y, v.z, acc1.y);
    }
    float2 acc = make_float2(acc0.x + acc1.x, acc0.y + acc1.y);
    acc.x += __shfl_xor(acc.x, 1);  // combine K-halves; both lanes get full sum
    acc.y += __shfl_xor(acc.y, 1);
    float w = fmaf(nl2, fmaf(ym.x, ym.x, ym.y * ym.y), om);
    return make_float2(acc.x - w * ym.y, acc.y + w * ym.x);
}

__device__ void ode_lds(int b, int lane,
                        const float* __restrict__ A0r,
                        const float* __restrict__ A0i,
                        const float* __restrict__ omega,
                        const float* __restrict__ nln,
                        float* __restrict__ out, long long out_size) {
    const int m = lane >> 1;
    const int h = lane & 1;

    float2 t2h[16];
#pragma unroll
    for (int j = 0; j < 16; ++j) t2h[j] = g_T2[m * NMODES + h * 16 + j];

    const float om = omega[m];
    const float nl = nln[0];
    const float nl2 = nl * nl;
    const float dt = 1.0f / 199.0f;
    const float hdt = 0.5f * dt;
    const float sdt = dt / 6.0f;

    float2 a;
    if (m < 24) a = make_float2(A0r[b * 24 + m], A0i[b * 24 + m]);
    else        a = make_float2(1.0f, 0.0f);

    __shared__ __align__(16) float2 xbuf[36];  // 32 complex + 2-slot pad at 16
    const int swi = m + ((m >= 16) ? 2 : 0);   // write slot for mode m
    const float4* xq = reinterpret_cast<const float4*>(xbuf) + 9 * h;  // h=1 -> byte 144

    if (h == 0) {
        long long o0 = (long long)b * 32 + m;
        if (o0 < out_size) out[o0] = a.x;
        xbuf[swi] = a;
    }
    __syncthreads();

    long long o = (long long)b * 32 + m;
    for (int t = 1; t < 200; ++t) {
        float2 k1 = f_eval_lds(xq, a, t2h, om, nl2);
        float2 y2 = make_float2(fmaf(hdt, k1.x, a.x), fmaf(hdt, k1.y, a.y));
        if (h == 0) xbuf[swi] = y2;
        __syncthreads();

        float2 k2 = f_eval_lds(xq, y2, t2h, om, nl2);
        float2 y3 = make_float2(fmaf(hdt, k2.x, a.x), fmaf(hdt, k2.y, a.y));
        if (h == 0) xbuf[swi] = y3;
        __syncthreads();

        float2 k3 = f_eval_lds(xq, y3, t2h, om, nl2);
        float2 y4 = make_float2(fmaf(dt, k3.x, a.x), fmaf(dt, k3.y, a.y));
        if (h == 0) xbuf[swi] = y4;
        __syncthreads();

        float2 k4 = f_eval_lds(xq, y4, t2h, om, nl2);

        a.x = fmaf(sdt, k1.x + 2.0f * k2.x + 2.0f * k3.x + k4.x, a.x);
        a.y = fmaf(sdt, k1.y + 2.0f * k2.y + 2.0f * k3.y + k4.y, a.y);

        o += 65536;  // 2048 * 32
        if (h == 0) {
            xbuf[swi] = a;
            if (o < out_size) out[o] = a.x;
        }
        __syncthreads();
    }
}

// ------------------------------ dispatcher ---------------------------------
__global__ __launch_bounds__(64) void ode_kernel(const float* __restrict__ A0r,
                                                 const float* __restrict__ A0i,
                                                 const float* __restrict__ omega,
                                                 const float* __restrict__ nln,
                                                 float* __restrict__ out,
                                                 long long out_size) {
    const int lane = threadIdx.x;
    const int b = blockIdx.x;
    // Parity-interleaved pipe mix: even blocks VALU-heavy (DPP tree), odd
    // blocks DS-heavy (LDS-staged). Block-uniform branch -> barriers legal.
    if ((b & 1) == 0) {
        ode_dpp(b, lane, A0r, A0i, omega, nln, out, out_size);
    } else {
        ode_lds(b, lane, A0r, A0i, omega, nln, out, out_size);
    }
}

extern "C" void kernel_launch(void* const* d_in, const int* in_sizes, int n_in,
                              void* d_out, int out_size, void* d_ws, size_t ws_size,
                              hipStream_t stream) {
    const float* A0r = (const float*)d_in[0];
    const float* A0i = (const float*)d_in[1];
    const float* omega = (const float*)d_in[2];
    const float* kappa = (const float*)d_in[3];
    const float* nln = (const float*)d_in[4];
    const float* params = (const float*)d_in[5];

    setup_kernel<<<1, 1024, 0, stream>>>(params, kappa);
    ode_kernel<<<2048, 64, 0, stream>>>(A0r, A0i, omega, nln,
                                        (float*)d_out, (long long)out_size);
}